// Round 1
// baseline (203.720 us; speedup 1.0000x reference)
//
#include <hip/hip_runtime.h>

// Problem constants (B=4, Tq=Tk=512, Q=K=1024, C=256)
#define M_ROWS 2048   // B*Tq = B*Tk
#define KDIM   1024
#define CDIM   256
#define TQ     512
#define TK     512

// tanh via native transcendentals: tanh(x) = 1 - 2/(exp(2x)+1)
// exp(2x) = exp2(x * 2*log2(e)). Saturates correctly for |x| large:
//  x>>0: e=inf -> rcp=0 -> 1 ;  x<<0: e=0 -> rcp(1)=1 -> -1.
__device__ __forceinline__ float tanh_fast(float x) {
    float e = __builtin_amdgcn_exp2f(x * 2.88539008177792681f);
    float r = __builtin_amdgcn_rcpf(e + 1.0f);
    return __builtin_fmaf(-2.0f, r, 1.0f);
}

// GEMM with transposed output: OT[n][m] = sum_k A[m][k] * W[k][n]
// A: (2048, 1024) row-major. W: (1024, 256) row-major. OT: (256, 2048).
// blockIdx.z selects (query,Wq,q2T) vs (key,Wk,k2T).
__global__ __launch_bounds__(256) void gemm_t_kernel(
    const float* __restrict__ Aq, const float* __restrict__ Ak,
    const float* __restrict__ Wq, const float* __restrict__ Wk,
    float* __restrict__ q2T, float* __restrict__ k2T)
{
    __shared__ float As[32][36];  // [k][m], pad to 36 for conflict-free
    __shared__ float Ws[32][36];  // [k][n]

    const float* A  = (blockIdx.z == 0) ? Aq : Ak;
    const float* W  = (blockIdx.z == 0) ? Wq : Wk;
    float*       OT = (blockIdx.z == 0) ? q2T : k2T;

    const int t  = threadIdx.x;
    const int m0 = blockIdx.x * 32;
    const int n0 = blockIdx.y * 32;
    const int tm = t & 15;        // 0..15 -> m pair
    const int tn = t >> 4;        // 0..15 -> n pair
    const int lr = t >> 3;        // 0..31 tile row for loads
    const int lc = (t & 7) * 4;   // 0,4,..,28 tile col*4 for loads

    float acc00 = 0.f, acc01 = 0.f, acc10 = 0.f, acc11 = 0.f;

    for (int k0 = 0; k0 < KDIM; k0 += 32) {
        float4 av = *(const float4*)&A[(size_t)(m0 + lr) * KDIM + k0 + lc];
        float4 wv = *(const float4*)&W[(size_t)(k0 + lr) * CDIM + n0 + lc];
        __syncthreads();                     // previous-iter reads done
        As[lc + 0][lr] = av.x;               // transpose A tile into [k][m]
        As[lc + 1][lr] = av.y;
        As[lc + 2][lr] = av.z;
        As[lc + 3][lr] = av.w;
        *(float4*)&Ws[lr][lc] = wv;
        __syncthreads();
        #pragma unroll
        for (int k = 0; k < 32; ++k) {
            float2 a2 = *(const float2*)&As[k][2 * tm];
            float2 w2 = *(const float2*)&Ws[k][2 * tn];
            acc00 = __builtin_fmaf(a2.x, w2.x, acc00);
            acc01 = __builtin_fmaf(a2.x, w2.y, acc01);
            acc10 = __builtin_fmaf(a2.y, w2.x, acc10);
            acc11 = __builtin_fmaf(a2.y, w2.y, acc11);
        }
    }

    // OT[n][m], m-contiguous float2 stores
    float2 r0 = make_float2(acc00, acc10);
    float2 r1 = make_float2(acc01, acc11);
    *(float2*)&OT[(size_t)(n0 + 2 * tn    ) * M_ROWS + m0 + 2 * tm] = r0;
    *(float2*)&OT[(size_t)(n0 + 2 * tn + 1) * M_ROWS + m0 + 2 * tm] = r1;
}

// Main: scores[b][q][k] = b + sum_c w[c] * tanh(q2T[c][b*512+q] + k2T[c][b*512+k])
// Block = 32x32 (q,k) tile, 256 threads each computing a 2x2 output tile.
// c processed in 4 chunks of 64 through LDS.
__global__ __launch_bounds__(256) void bahdanau_kernel(
    const float* __restrict__ q2T, const float* __restrict__ k2T,
    const float* __restrict__ w_attn, const float* __restrict__ b_attn,
    float* __restrict__ out)
{
    __shared__ float qs[64][36];  // [c_local][q_local], pad 36
    __shared__ float ks[64][36];  // [c_local][k_local]
    __shared__ float wl[CDIM];

    const int t  = threadIdx.x;
    const int b  = blockIdx.z;
    const int q0 = blockIdx.x * 32;
    const int k0 = blockIdx.y * 32;
    const int gq = b * TQ + q0;   // global column base into q2T
    const int gk = b * TK + k0;
    const int tq = t & 15;        // q pair
    const int tk = t >> 4;        // k pair
    const int lr = t >> 3;        // 0..31 c-row for loads
    const int lc = (t & 7) * 4;   // col*4 for loads

    wl[t] = w_attn[t];            // CDIM == blockDim.x == 256

    float a00 = 0.f, a01 = 0.f, a10 = 0.f, a11 = 0.f;

    for (int c0 = 0; c0 < CDIM; c0 += 64) {
        float4 qv0 = *(const float4*)&q2T[(size_t)(c0 + lr     ) * M_ROWS + gq + lc];
        float4 qv1 = *(const float4*)&q2T[(size_t)(c0 + lr + 32) * M_ROWS + gq + lc];
        float4 kv0 = *(const float4*)&k2T[(size_t)(c0 + lr     ) * M_ROWS + gk + lc];
        float4 kv1 = *(const float4*)&k2T[(size_t)(c0 + lr + 32) * M_ROWS + gk + lc];
        __syncthreads();
        *(float4*)&qs[lr     ][lc] = qv0;
        *(float4*)&qs[lr + 32][lc] = qv1;
        *(float4*)&ks[lr     ][lc] = kv0;
        *(float4*)&ks[lr + 32][lc] = kv1;
        __syncthreads();
        #pragma unroll 8
        for (int c = 0; c < 64; ++c) {
            float2 qp = *(const float2*)&qs[c][2 * tq];
            float2 kp = *(const float2*)&ks[c][2 * tk];
            float w = wl[c0 + c];
            a00 = __builtin_fmaf(w, tanh_fast(qp.x + kp.x), a00);
            a01 = __builtin_fmaf(w, tanh_fast(qp.x + kp.y), a01);
            a10 = __builtin_fmaf(w, tanh_fast(qp.y + kp.x), a10);
            a11 = __builtin_fmaf(w, tanh_fast(qp.y + kp.y), a11);
        }
    }

    const float bb = *b_attn;
    float* o = out + ((size_t)b * TQ + q0) * TK + k0;
    *(float2*)&o[(2 * tq    ) * TK + 2 * tk] = make_float2(a00 + bb, a01 + bb);
    *(float2*)&o[(2 * tq + 1) * TK + 2 * tk] = make_float2(a10 + bb, a11 + bb);
}

extern "C" void kernel_launch(void* const* d_in, const int* in_sizes, int n_in,
                              void* d_out, int out_size, void* d_ws, size_t ws_size,
                              hipStream_t stream) {
    const float* query  = (const float*)d_in[0];
    const float* key    = (const float*)d_in[1];
    const float* Wq     = (const float*)d_in[2];
    const float* Wk     = (const float*)d_in[3];
    const float* w_attn = (const float*)d_in[4];
    const float* b_attn = (const float*)d_in[5];
    float* out = (float*)d_out;

    float* q2T = (float*)d_ws;               // 256 x 2048 fp32 = 2 MB
    float* k2T = q2T + (size_t)CDIM * M_ROWS; // 256 x 2048 fp32 = 2 MB

    dim3 gemm_grid(M_ROWS / 32, CDIM / 32, 2);   // 64 x 8 x 2 = 1024 blocks
    gemm_t_kernel<<<gemm_grid, 256, 0, stream>>>(query, key, Wq, Wk, q2T, k2T);

    dim3 main_grid(TQ / 32, TK / 32, 4);         // 16 x 16 x 4 = 1024 blocks
    bahdanau_kernel<<<main_grid, 256, 0, stream>>>(q2T, k2T, w_attn, b_attn, out);
}

// Round 2
// 165.890 us; speedup vs baseline: 1.2280x; 1.2280x over previous
//
#include <hip/hip_runtime.h>

// Problem constants (B=4, Tq=Tk=512, Q=K=1024, C=256)
#define M_ROWS 2048   // B*Tq = B*Tk
#define KDIM   1024
#define CDIM   256
#define TQ     512
#define TK     512

#define BM 64
#define BN 32
#define BK 32

// 2*log2(e): folded into GEMM epilogue so tanh needs no multiply.
#define SCALE2LOG2E 2.8853900817779268f

// GEMM with transposed, pre-scaled output: OT[n][m] = S * sum_k A[m][k]*W[k][n]
// A: (2048,1024) rm. W: (1024,256) rm. OT: (256,2048).
// 64x32 tile, 256 thr, 4x2/thread -> FMA-bound (LDS clk ~= FMA clk), 512 blocks.
__global__ __launch_bounds__(256) void gemm_t_kernel(
    const float* __restrict__ Aq, const float* __restrict__ Ak,
    const float* __restrict__ Wq, const float* __restrict__ Wk,
    float* __restrict__ q2T, float* __restrict__ k2T)
{
    __shared__ float As[BK][BM + 4];  // [k][m], pad 68 words
    __shared__ float Ws[BK][BN + 4];  // [k][n], pad 36 words

    const float* A  = (blockIdx.z == 0) ? Aq : Ak;
    const float* W  = (blockIdx.z == 0) ? Wq : Wk;
    float*       OT = (blockIdx.z == 0) ? q2T : k2T;

    const int t  = threadIdx.x;
    const int m0 = blockIdx.x * BM;
    const int n0 = blockIdx.y * BN;
    const int tx = t & 15;        // m group: rows 4*tx..4*tx+3
    const int ty = t >> 4;        // n group: cols 2*ty..2*ty+1
    const int am = t >> 2;        // 0..63  A-load row
    const int ak = (t & 3) * 4;   // 0,4,8,12 A-load col*4
    const int wk = t >> 3;        // 0..31  W-load row
    const int wn = (t & 7) * 4;   // W-load col*4

    float acc[4][2] = {};

    for (int k0 = 0; k0 < KDIM; k0 += BK) {
        float4 av0 = *(const float4*)&A[(size_t)(m0 + am) * KDIM + k0 + ak];
        float4 av1 = *(const float4*)&A[(size_t)(m0 + am) * KDIM + k0 + ak + 16];
        float4 wv  = *(const float4*)&W[(size_t)(k0 + wk) * CDIM + n0 + wn];
        __syncthreads();                       // previous-iter reads done
        As[ak +  0][am] = av0.x; As[ak +  1][am] = av0.y;
        As[ak +  2][am] = av0.z; As[ak +  3][am] = av0.w;
        As[ak + 16][am] = av1.x; As[ak + 17][am] = av1.y;
        As[ak + 18][am] = av1.z; As[ak + 19][am] = av1.w;
        *(float4*)&Ws[wk][wn] = wv;
        __syncthreads();
        #pragma unroll
        for (int k = 0; k < BK; ++k) {
            float4 a4 = *(const float4*)&As[k][4 * tx];
            float2 w2 = *(const float2*)&Ws[k][2 * ty];
            acc[0][0] = __builtin_fmaf(a4.x, w2.x, acc[0][0]);
            acc[1][0] = __builtin_fmaf(a4.y, w2.x, acc[1][0]);
            acc[2][0] = __builtin_fmaf(a4.z, w2.x, acc[2][0]);
            acc[3][0] = __builtin_fmaf(a4.w, w2.x, acc[3][0]);
            acc[0][1] = __builtin_fmaf(a4.x, w2.y, acc[0][1]);
            acc[1][1] = __builtin_fmaf(a4.y, w2.y, acc[1][1]);
            acc[2][1] = __builtin_fmaf(a4.z, w2.y, acc[2][1]);
            acc[3][1] = __builtin_fmaf(a4.w, w2.y, acc[3][1]);
        }
    }

    #pragma unroll
    for (int j = 0; j < 2; ++j) {
        float4 o = make_float4(acc[0][j] * SCALE2LOG2E, acc[1][j] * SCALE2LOG2E,
                               acc[2][j] * SCALE2LOG2E, acc[3][j] * SCALE2LOG2E);
        *(float4*)&OT[(size_t)(n0 + 2 * ty + j) * M_ROWS + m0 + 4 * tx] = o;
    }
}

// scores[b][q][k] = b_attn + sum_c w_c*tanh(q_c+k_c)
//                 = (b_attn + sum_c w_c) + sum_c rcp(fma(e_c, s_c, s_c))
// where e_c = exp2(q'_c + k'_c) (inputs pre-scaled by 2*log2e), s_c = -0.5/w_c.
// Per element: add, exp2, fma, rcp, add  (22 cyc/wave64).
__global__ __launch_bounds__(256) void bahdanau_kernel(
    const float* __restrict__ q2T, const float* __restrict__ k2T,
    const float* __restrict__ w_attn, const float* __restrict__ b_attn,
    float* __restrict__ out)
{
    __shared__ float qs[64][36];  // [c_local][q_local]
    __shared__ float ks[64][36];  // [c_local][k_local]
    __shared__ float sl[CDIM];    // s_c = -0.5/w_c
    __shared__ float partial[4];  // per-wave w sums

    const int t  = threadIdx.x;
    const int b  = blockIdx.z;
    const int q0 = blockIdx.x * 32;
    const int k0 = blockIdx.y * 32;
    const int gq = b * TQ + q0;
    const int gk = b * TK + k0;
    const int tq = t & 15;        // q pair
    const int tk = t >> 4;        // k pair
    const int lr = t >> 3;        // 0..31 c-row for loads
    const int lc = (t & 7) * 4;   // col*4 for loads

    // prologue: s_c and sum(w) (CDIM == blockDim.x == 256)
    {
        float wv = w_attn[t];
        sl[t] = -0.5f / wv;
        float sum = wv;
        #pragma unroll
        for (int o = 32; o >= 1; o >>= 1) sum += __shfl_down(sum, o);
        if ((t & 63) == 0) partial[t >> 6] = sum;
    }

    float a00 = 0.f, a01 = 0.f, a10 = 0.f, a11 = 0.f;

    for (int c0 = 0; c0 < CDIM; c0 += 64) {
        float4 qv0 = *(const float4*)&q2T[(size_t)(c0 + lr     ) * M_ROWS + gq + lc];
        float4 qv1 = *(const float4*)&q2T[(size_t)(c0 + lr + 32) * M_ROWS + gq + lc];
        float4 kv0 = *(const float4*)&k2T[(size_t)(c0 + lr     ) * M_ROWS + gk + lc];
        float4 kv1 = *(const float4*)&k2T[(size_t)(c0 + lr + 32) * M_ROWS + gk + lc];
        __syncthreads();
        *(float4*)&qs[lr     ][lc] = qv0;
        *(float4*)&qs[lr + 32][lc] = qv1;
        *(float4*)&ks[lr     ][lc] = kv0;
        *(float4*)&ks[lr + 32][lc] = kv1;
        __syncthreads();
        #pragma unroll 16
        for (int c = 0; c < 64; ++c) {
            float2 qp = *(const float2*)&qs[c][2 * tq];
            float2 kp = *(const float2*)&ks[c][2 * tk];
            float s = sl[c0 + c];
            float e00 = __builtin_amdgcn_exp2f(qp.x + kp.x);
            float e01 = __builtin_amdgcn_exp2f(qp.x + kp.y);
            float e10 = __builtin_amdgcn_exp2f(qp.y + kp.x);
            float e11 = __builtin_amdgcn_exp2f(qp.y + kp.y);
            a00 += __builtin_amdgcn_rcpf(__builtin_fmaf(e00, s, s));
            a01 += __builtin_amdgcn_rcpf(__builtin_fmaf(e01, s, s));
            a10 += __builtin_amdgcn_rcpf(__builtin_fmaf(e10, s, s));
            a11 += __builtin_amdgcn_rcpf(__builtin_fmaf(e11, s, s));
        }
    }

    const float bias2 = *b_attn + partial[0] + partial[1] + partial[2] + partial[3];
    float* o = out + ((size_t)b * TQ + q0) * TK + k0;
    *(float2*)&o[(2 * tq    ) * TK + 2 * tk] = make_float2(a00 + bias2, a01 + bias2);
    *(float2*)&o[(2 * tq + 1) * TK + 2 * tk] = make_float2(a10 + bias2, a11 + bias2);
}

extern "C" void kernel_launch(void* const* d_in, const int* in_sizes, int n_in,
                              void* d_out, int out_size, void* d_ws, size_t ws_size,
                              hipStream_t stream) {
    const float* query  = (const float*)d_in[0];
    const float* key    = (const float*)d_in[1];
    const float* Wq     = (const float*)d_in[2];
    const float* Wk     = (const float*)d_in[3];
    const float* w_attn = (const float*)d_in[4];
    const float* b_attn = (const float*)d_in[5];
    float* out = (float*)d_out;

    float* q2T = (float*)d_ws;                 // 256 x 2048 fp32 = 2 MB
    float* k2T = q2T + (size_t)CDIM * M_ROWS;  // 256 x 2048 fp32 = 2 MB

    dim3 gemm_grid(M_ROWS / BM, CDIM / BN, 2);   // 32 x 8 x 2 = 512 blocks
    gemm_t_kernel<<<gemm_grid, 256, 0, stream>>>(query, key, Wq, Wk, q2T, k2T);

    dim3 main_grid(TQ / 32, TK / 32, 4);         // 16 x 16 x 4 = 1024 blocks
    bahdanau_kernel<<<main_grid, 256, 0, stream>>>(q2T, k2T, w_attn, b_attn, out);
}

// Round 3
// 124.314 us; speedup vs baseline: 1.6388x; 1.3344x over previous
//
#include <hip/hip_runtime.h>

// Problem constants (B=4, Tq=Tk=512, Q=K=1024, C=256)
#define M_ROWS 2048   // B*Tq = B*Tk
#define KDIM   1024
#define CDIM   256
#define TQ     512
#define TK     512

#define GBM 64        // m rows per block (gemm)
#define GBN 32        // c cols per block (gemm)
#define GBK 32        // k per stage

// 2*log2(e): tanh(x) = 1 - 2/(exp2(2log2e * x) + 1)
#define SCALE2LOG2E 2.8853900817779268f

typedef __attribute__((ext_vector_type(8))) short short8;
typedef __attribute__((ext_vector_type(4))) float floatx4;
typedef __attribute__((ext_vector_type(2))) float f32x2;

__device__ __forceinline__ short f2bf(float f) {
    unsigned x = __builtin_bit_cast(unsigned, f);
    unsigned r = (x + 0x7FFFu + ((x >> 16) & 1u)) >> 16;   // RNE
    return (short)r;
}

// MFMA GEMM producing E[c][m] = exp2(S * sum_k A[m][k]*W[k][c]),
// q-side additionally prescaled by s_c = -0.5/w_c.
// D[i=c][j=m] via mfma_f32_16x16x32_bf16:
//   A-op: A[i=lane&15][k=quad*8+jj] = W^T  -> Ws[c][k] k-contiguous
//   B-op: B[k=quad*8+jj][j=lane&15] = A^T  -> As[m][k] k-contiguous
//   D   : col j = lane&15, row i = quad*4+reg
__global__ __launch_bounds__(256) void gemm_mfma_kernel(
    const float* __restrict__ Aq, const float* __restrict__ Ak,
    const float* __restrict__ Wq, const float* __restrict__ Wk,
    const float* __restrict__ w_attn,
    float* __restrict__ Eq, float* __restrict__ Ek)
{
    __shared__ short As[GBM][GBK + 8];   // [m][k] pad->40 shorts (80B rows)
    __shared__ short Ws[GBN][GBK + 8];   // [c][k]

    const int z = blockIdx.z;
    const float* A = z ? Ak : Aq;
    const float* W = z ? Wk : Wq;
    float*       E = z ? Ek : Eq;

    const int t    = threadIdx.x;
    const int lane = t & 63;
    const int wave = t >> 6;
    const int m0   = blockIdx.x * GBM;
    const int n0   = blockIdx.y * GBN;

    const int ar = t >> 2;            // A stage: row 0..63
    const int ac = (t & 3) * 8;       // A stage: k col 0,8,16,24
    const int wr = t >> 3;            // W stage: k row 0..31
    const int wc = (t & 7) * 4;       // W stage: c col 0,4,..,28

    const int iw = wave & 1;          // c subtile (16)
    const int jw = wave >> 1;         // m subtile pair (32)
    const int li = lane & 15;
    const int qd = lane >> 4;

    floatx4 acc0 = {0.f, 0.f, 0.f, 0.f};
    floatx4 acc1 = {0.f, 0.f, 0.f, 0.f};

    for (int k0 = 0; k0 < KDIM; k0 += GBK) {
        float4 a0 = *(const float4*)&A[(size_t)(m0 + ar) * KDIM + k0 + ac];
        float4 a1 = *(const float4*)&A[(size_t)(m0 + ar) * KDIM + k0 + ac + 4];
        float4 w0 = *(const float4*)&W[(size_t)(k0 + wr) * CDIM + n0 + wc];
        __syncthreads();                       // previous-iter LDS reads done
        short8 av = { f2bf(a0.x), f2bf(a0.y), f2bf(a0.z), f2bf(a0.w),
                      f2bf(a1.x), f2bf(a1.y), f2bf(a1.z), f2bf(a1.w) };
        *(short8*)&As[ar][ac] = av;
        Ws[wc + 0][wr] = f2bf(w0.x);           // 80B row stride -> banks 20 apart
        Ws[wc + 1][wr] = f2bf(w0.y);
        Ws[wc + 2][wr] = f2bf(w0.z);
        Ws[wc + 3][wr] = f2bf(w0.w);
        __syncthreads();
        short8 af  = *(const short8*)&Ws[iw * 16 + li][qd * 8];
        short8 bf0 = *(const short8*)&As[jw * 32 + li][qd * 8];
        short8 bf1 = *(const short8*)&As[jw * 32 + 16 + li][qd * 8];
        acc0 = __builtin_amdgcn_mfma_f32_16x16x32_bf16(af, bf0, acc0, 0, 0, 0);
        acc1 = __builtin_amdgcn_mfma_f32_16x16x32_bf16(af, bf1, acc1, 0, 0, 0);
    }

    #pragma unroll
    for (int r = 0; r < 4; ++r) {
        const int c = n0 + iw * 16 + qd * 4 + r;
        float scale = z ? 1.0f : (-0.5f / w_attn[c]);
        float v0 = __builtin_amdgcn_exp2f(acc0[r] * SCALE2LOG2E) * scale;
        float v1 = __builtin_amdgcn_exp2f(acc1[r] * SCALE2LOG2E) * scale;
        E[(size_t)c * M_ROWS + m0 + jw * 32 + li]      = v0;
        E[(size_t)c * M_ROWS + m0 + jw * 32 + 16 + li] = v1;
    }
}

// scores[b][q][k] = (b_attn + sum_c w_c) + sum_c rcp(fma(Eqs[c][q], Ek[c][k], s_c))
// Eqs = s_c * e^{2 q2ctx}, Ek = e^{2 k2ctx}, s_c = -0.5/w_c.
// Per element: fma, rcp, add (rcp is the floor).
__global__ __launch_bounds__(256) void bahdanau_kernel(
    const float* __restrict__ Eqs, const float* __restrict__ Ek,
    const float* __restrict__ w_attn, const float* __restrict__ b_attn,
    float* __restrict__ out)
{
    __shared__ float qs[64][36];  // [c_local][q_local]
    __shared__ float ks[64][36];  // [c_local][k_local]
    __shared__ float sl[CDIM];    // s_c = -0.5/w_c
    __shared__ float partial[4];  // per-wave w sums

    const int t  = threadIdx.x;
    const int b  = blockIdx.z;
    const int q0 = blockIdx.x * 32;
    const int k0 = blockIdx.y * 32;
    const int gq = b * TQ + q0;
    const int gk = b * TK + k0;
    const int tq = t & 15;        // q pair
    const int tk = t >> 4;        // k pair
    const int lr = t >> 3;        // 0..31 c-row for loads
    const int lc = (t & 7) * 4;   // col*4 for loads

    {   // prologue: s_c and sum(w); CDIM == blockDim.x == 256
        float wv = w_attn[t];
        sl[t] = -0.5f / wv;
        float sum = wv;
        #pragma unroll
        for (int o = 32; o >= 1; o >>= 1) sum += __shfl_down(sum, o);
        if ((t & 63) == 0) partial[t >> 6] = sum;
    }

    f32x2 a0 = {0.f, 0.f};   // (q0,k0),(q1,k0)
    f32x2 a1 = {0.f, 0.f};   // (q0,k1),(q1,k1)

    for (int c0 = 0; c0 < CDIM; c0 += 64) {
        float4 qv0 = *(const float4*)&Eqs[(size_t)(c0 + lr     ) * M_ROWS + gq + lc];
        float4 qv1 = *(const float4*)&Eqs[(size_t)(c0 + lr + 32) * M_ROWS + gq + lc];
        float4 kv0 = *(const float4*)&Ek [(size_t)(c0 + lr     ) * M_ROWS + gk + lc];
        float4 kv1 = *(const float4*)&Ek [(size_t)(c0 + lr + 32) * M_ROWS + gk + lc];
        __syncthreads();
        *(float4*)&qs[lr     ][lc] = qv0;
        *(float4*)&qs[lr + 32][lc] = qv1;
        *(float4*)&ks[lr     ][lc] = kv0;
        *(float4*)&ks[lr + 32][lc] = kv1;
        __syncthreads();
        #pragma unroll 16
        for (int c = 0; c < 64; ++c) {
            f32x2 qp = *(const f32x2*)&qs[c][2 * tq];
            f32x2 kp = *(const f32x2*)&ks[c][2 * tk];
            float s  = sl[c0 + c];
            f32x2 sv  = {s, s};
            f32x2 kxx = {kp.x, kp.x};
            f32x2 kyy = {kp.y, kp.y};
            f32x2 f0 = __builtin_elementwise_fma(qp, kxx, sv);
            f32x2 f1 = __builtin_elementwise_fma(qp, kyy, sv);
            f32x2 r0 = {__builtin_amdgcn_rcpf(f0.x), __builtin_amdgcn_rcpf(f0.y)};
            f32x2 r1 = {__builtin_amdgcn_rcpf(f1.x), __builtin_amdgcn_rcpf(f1.y)};
            a0 += r0;
            a1 += r1;
        }
    }

    const float bias2 = *b_attn + partial[0] + partial[1] + partial[2] + partial[3];
    float* o = out + ((size_t)b * TQ + q0) * TK + k0;
    *(float2*)&o[(2 * tq    ) * TK + 2 * tk] = make_float2(a0.x + bias2, a1.x + bias2);
    *(float2*)&o[(2 * tq + 1) * TK + 2 * tk] = make_float2(a0.y + bias2, a1.y + bias2);
}

extern "C" void kernel_launch(void* const* d_in, const int* in_sizes, int n_in,
                              void* d_out, int out_size, void* d_ws, size_t ws_size,
                              hipStream_t stream) {
    const float* query  = (const float*)d_in[0];
    const float* key    = (const float*)d_in[1];
    const float* Wq     = (const float*)d_in[2];
    const float* Wk     = (const float*)d_in[3];
    const float* w_attn = (const float*)d_in[4];
    const float* b_attn = (const float*)d_in[5];
    float* out = (float*)d_out;

    float* Eqs = (float*)d_ws;                 // 256 x 2048 fp32 = 2 MB
    float* Ek  = Eqs + (size_t)CDIM * M_ROWS;  // 256 x 2048 fp32 = 2 MB

    dim3 gemm_grid(M_ROWS / GBM, CDIM / GBN, 2);   // 32 x 8 x 2 = 512 blocks
    gemm_mfma_kernel<<<gemm_grid, 256, 0, stream>>>(query, key, Wq, Wk, w_attn, Eqs, Ek);

    dim3 main_grid(TQ / 32, TK / 32, 4);           // 16 x 16 x 4 = 1024 blocks
    bahdanau_kernel<<<main_grid, 256, 0, stream>>>(Eqs, Ek, w_attn, b_attn, out);
}